// Round 1
// 1595.740 us; speedup vs baseline: 1.3690x; 1.3690x over previous
//
#include <hip/hip_runtime.h>
#include <hip/hip_bf16.h>

typedef __bf16 bf16_t;
typedef __attribute__((ext_vector_type(8))) __bf16 bf16x8;
typedef __attribute__((ext_vector_type(4))) __bf16 bf16x4;
typedef __attribute__((ext_vector_type(4))) float f32x4;

#define O_N 100000
#define T_N 200000
#define LDA 72   // padded LDS row stride (elems): 144B -> 2-way bank aliasing (free, m136)

__device__ __forceinline__ bf16x8 cvt8(const float* p) {
    f32x4 a = *(const f32x4*)p;
    f32x4 b = *(const f32x4*)(p + 4);
    bf16x8 v;
    v[0] = (bf16_t)a[0]; v[1] = (bf16_t)a[1]; v[2] = (bf16_t)a[2]; v[3] = (bf16_t)a[3];
    v[4] = (bf16_t)b[0]; v[5] = (bf16_t)b[1]; v[6] = (bf16_t)b[2]; v[7] = (bf16_t)b[3];
    return v;
}

// MODE 1: A = gather-concat(objF[s]|predF|objF[o]) f32->bf16 -> CoutB = h (bf16)
// MODE 2: A = h (bf16); MFMA operand-swapped (transposed C in regs):
//         lane holds 4 consecutive n-cols for one edge row ->
//         n-blocks 0-3: bf16x4 store to newT cols 0-511 (new_s);
//         block 4: f32x4 -> newp; blocks 5-8: bf16x4 store to newT cols 512-1023 (new_o).
//         NO atomics (pooling done by CSR gather pool_k).  CoutB = newT.
// MODE 3: A = pooledB (bf16) * 1/max(counts,1) (fused div) -> CoutB = t3 (bf16)
// MODE 4: A = t3 (bf16) -> CoutF = new_obj (f32)
// MODE 5: legacy atomic-scatter epilogue (small-workspace fallback only)
template<int MODE, int N, int K>
__launch_bounds__(256)
__global__ void gemm_k(const bf16_t* __restrict__ A,
                       const float*  __restrict__ AobjF,
                       const float*  __restrict__ ApredF,
                       const int*    __restrict__ edges,
                       const float*  __restrict__ countsIn,
                       const bf16_t* __restrict__ Bt,     // N x K row-major bf16
                       const float*  __restrict__ bias,   // length N, f32
                       bf16_t*       __restrict__ CoutB,  // MODE1: h, MODE2: newT, MODE3: t3
                       float*        __restrict__ CoutF,  // MODE2/5: newp base; MODE4: new_obj
                       int M)
{
    __shared__ bf16_t lA[128 * LDA];
    __shared__ bf16_t lB[128 * LDA];
    __shared__ int sIdxL[128], oIdxL[128];

    const int tid  = threadIdx.x;
    const int lane = tid & 63;
    const int wv   = tid >> 6;
    const int wr   = (wv >> 1) * 64;   // wave row base in 128-tile
    const int wc   = (wv & 1) * 64;    // wave col base
    const int fr   = lane & 15;        // m/n within 16-tile
    const int fk   = (lane >> 4) * 8;  // k offset within 32
    const int mbase = blockIdx.y * 128;
    const int nbase = blockIdx.x * 128;

    if constexpr (MODE == 1 || MODE == 5) {
        if (tid < 128) {
            int g = mbase + tid; if (g > M - 1) g = M - 1;
            sIdxL[tid] = edges[2 * g];
            oIdxL[tid] = edges[2 * g + 1];
        }
    }
    __syncthreads();

    f32x4 acc[4][4];
    #pragma unroll
    for (int i = 0; i < 4; i++)
        #pragma unroll
        for (int j = 0; j < 4; j++)
            acc[i][j] = (f32x4){0.f, 0.f, 0.f, 0.f};

    const int KT = K / 64;
    for (int kt = 0; kt < KT; ++kt) {
        const int k0 = kt * 64;
        // ---- stage A tile (128 rows x 64 k) : 8 elems/thread x4 ----
        #pragma unroll
        for (int t = 0; t < 4; ++t) {
            int e   = t * 2048 + tid * 8;
            int row = e >> 6;
            int col = e & 63;
            int grow = mbase + row; if (grow > M - 1) grow = M - 1;
            bf16x8 v;
            if constexpr (MODE == 1) {
                int k = k0 + col;  // 64-chunk lies in one 128-wide segment
                const float* gp;
                if (k < 128)      gp = AobjF  + (size_t)sIdxL[row] * 128 + k;
                else if (k < 256) gp = ApredF + (size_t)grow * 128 + (k - 128);
                else              gp = AobjF  + (size_t)oIdxL[row] * 128 + (k - 256);
                v = cvt8(gp);
            } else if constexpr (MODE == 3) {
                const bf16_t* pr = A + (size_t)grow * 512 + k0 + col;
                float c = countsIn[grow]; c = c > 1.f ? c : 1.f;
                float rc = 1.f / c;
                bf16x8 raw = *(const bf16x8*)pr;
                #pragma unroll
                for (int l = 0; l < 8; l++) v[l] = (bf16_t)((float)raw[l] * rc);
            } else {
                v = *(const bf16x8*)(A + (size_t)grow * K + k0 + col);
            }
            *(bf16x8*)&lA[row * LDA + col] = v;
        }
        // ---- stage B tile (128 n x 64 k), bf16 source ----
        #pragma unroll
        for (int t = 0; t < 4; ++t) {
            int e   = t * 2048 + tid * 8;
            int row = e >> 6;
            int col = e & 63;
            bf16x8 v = *(const bf16x8*)(Bt + (size_t)(nbase + row) * K + k0 + col);
            *(bf16x8*)&lB[row * LDA + col] = v;
        }
        __syncthreads();

        #pragma unroll
        for (int ks = 0; ks < 64; ks += 32) {
            bf16x8 af[4], bf[4];
            #pragma unroll
            for (int i = 0; i < 4; i++)
                af[i] = *(const bf16x8*)&lA[(wr + i * 16 + fr) * LDA + ks + fk];
            #pragma unroll
            for (int j = 0; j < 4; j++)
                bf[j] = *(const bf16x8*)&lB[(wc + j * 16 + fr) * LDA + ks + fk];
            #pragma unroll
            for (int i = 0; i < 4; i++)
                #pragma unroll
                for (int j = 0; j < 4; j++) {
                    if constexpr (MODE == 2 || MODE == 5)
                        // swapped operands: acc holds C^T -> lane owns 4 consecutive n
                        acc[i][j] = __builtin_amdgcn_mfma_f32_16x16x32_bf16(
                            bf[j], af[i], acc[i][j], 0, 0, 0);
                    else
                        acc[i][j] = __builtin_amdgcn_mfma_f32_16x16x32_bf16(
                            af[i], bf[j], acc[i][j], 0, 0, 0);
                }
        }
        __syncthreads();
    }

    if constexpr (MODE == 2) {
        // transposed D: col(lane&15)=m (edge row), row((lane>>4)*4+r)=n (out col)
        // plain packed stores into newT [R][1024]: cols 0-511 = new_s, 512-1023 = new_o
        const bool isNewp = (nbase == 512);
        const int  cb     = (nbase < 512) ? nbase : (nbase - 128);
        #pragma unroll
        for (int j = 0; j < 4; j++) {
            int nl = wc + j * 16 + (lane >> 4) * 4;        // 4-aligned col offset
            f32x4 bv = *(const f32x4*)&bias[nbase + nl];
            #pragma unroll
            for (int i = 0; i < 4; i++) {
                int ml   = wr + i * 16 + fr;
                int grow = mbase + ml;
                if (grow >= M) continue;
                float v0 = acc[i][j][0] + bv[0]; v0 = v0 > 0.f ? v0 : 0.f;
                float v1 = acc[i][j][1] + bv[1]; v1 = v1 > 0.f ? v1 : 0.f;
                float v2 = acc[i][j][2] + bv[2]; v2 = v2 > 0.f ? v2 : 0.f;
                float v3 = acc[i][j][3] + bv[3]; v3 = v3 > 0.f ? v3 : 0.f;
                if (isNewp) {
                    f32x4 o = {v0, v1, v2, v3};
                    *(f32x4*)&CoutF[(size_t)grow * 128 + nl] = o;   // nbase+nl-512 == nl
                } else {
                    bf16x4 pv;
                    pv[0] = (bf16_t)v0; pv[1] = (bf16_t)v1;
                    pv[2] = (bf16_t)v2; pv[3] = (bf16_t)v3;
                    *(bf16x4*)&CoutB[(size_t)grow * 1024 + cb + nl] = pv;
                }
            }
        }
    } else if constexpr (MODE == 5) {
        // legacy atomic scatter (fallback path only)
        const bool isNewp = (nbase == 512);
        const bool isS    = (nbase < 512);
        const int* idxArr = isS ? sIdxL : oIdxL;
        const int  cb     = isS ? nbase : (nbase - 640);   // pooled col base
        #pragma unroll
        for (int j = 0; j < 4; j++) {
            int nl = wc + j * 16 + (lane >> 4) * 4;
            f32x4 bv = *(const f32x4*)&bias[nbase + nl];
            #pragma unroll
            for (int i = 0; i < 4; i++) {
                int ml   = wr + i * 16 + fr;
                int grow = mbase + ml;
                if (grow >= M) continue;
                float v0 = acc[i][j][0] + bv[0]; v0 = v0 > 0.f ? v0 : 0.f;
                float v1 = acc[i][j][1] + bv[1]; v1 = v1 > 0.f ? v1 : 0.f;
                float v2 = acc[i][j][2] + bv[2]; v2 = v2 > 0.f ? v2 : 0.f;
                float v3 = acc[i][j][3] + bv[3]; v3 = v3 > 0.f ? v3 : 0.f;
                if (isNewp) {
                    f32x4 o = {v0, v1, v2, v3};
                    *(f32x4*)&CoutF[(size_t)grow * 128 + nl] = o;
                } else {
                    int idx = idxArr[ml];
                    __hip_bfloat162 p0, p1;
                    p0.x = __float2bfloat16(v0); p0.y = __float2bfloat16(v1);
                    p1.x = __float2bfloat16(v2); p1.y = __float2bfloat16(v3);
                    __hip_bfloat162* base =
                        (__hip_bfloat162*)(CoutB + (size_t)idx * 512 + cb + nl);
                    unsafeAtomicAdd(base,     p0);
                    unsafeAtomicAdd(base + 1, p1);
                }
            }
        }
    } else {
        // normal D: col(lane&15)=n, row((lane>>4)*4+r)=m  [m89-verified]
        #pragma unroll
        for (int j = 0; j < 4; j++) {
            int col = nbase + wc + j * 16 + fr;
            float bval = bias[col];
            #pragma unroll
            for (int i = 0; i < 4; i++) {
                #pragma unroll
                for (int r = 0; r < 4; r++) {
                    int rl   = wr + i * 16 + (lane >> 4) * 4 + r;
                    int grow = mbase + rl;
                    if (grow >= M) continue;
                    float v = acc[i][j][r] + bval;
                    v = v > 0.f ? v : 0.f;
                    if constexpr (MODE == 4)
                        CoutF[(size_t)grow * N + col] = v;
                    else
                        CoutB[(size_t)grow * N + col] = (bf16_t)v;
                }
            }
        }
    }
}

// f32 in (K x N row-major) -> bf16 out (N x K row-major)
__global__ void transpose_k(const float* __restrict__ in, bf16_t* __restrict__ out,
                            int K, int N) {
    int idx = blockIdx.x * 256 + threadIdx.x;
    if (idx < K * N) {
        int k = idx / N, n = idx - k * N;
        out[n * K + k] = (bf16_t)in[idx];
    }
}

__global__ void counts_k(const int* __restrict__ edges, float* __restrict__ counts) {
    int t = blockIdx.x * 256 + threadIdx.x;
    if (t < T_N) {
        unsafeAtomicAdd(&counts[edges[2 * t]],     1.f);
        unsafeAtomicAdd(&counts[edges[2 * t + 1]], 1.f);
    }
}

// Exclusive prefix sum of (int)counts over O_N -> offsets[0..O_N], cursor=offsets.
// Single block of 1024 threads (16 waves); ~98 iterations, ~30 us. Fine vs 2.2 ms total.
__launch_bounds__(1024)
__global__ void scan_k(const float* __restrict__ counts, int* __restrict__ offsets,
                       int* __restrict__ cursor) {
    __shared__ int wsum[17];
    __shared__ int carry;
    const int tid = threadIdx.x, lane = tid & 63, wv = tid >> 6;
    if (tid == 0) carry = 0;
    for (int base = 0; base < O_N; base += 1024) {
        __syncthreads();                       // prev-iter wsum readers done
        int i = base + tid;
        int x = (i < O_N) ? (int)counts[i] : 0;
        int v = x;
        #pragma unroll
        for (int d = 1; d < 64; d <<= 1) {
            int u = __shfl_up(v, d, 64);
            if (lane >= d) v += u;
        }
        if (lane == 63) wsum[wv] = v;          // wave inclusive total
        __syncthreads();
        if (tid == 0) {                        // serial 16-elem exclusive scan
            int run = carry;
            #pragma unroll
            for (int k = 0; k < 16; ++k) { int t2 = wsum[k]; wsum[k] = run; run += t2; }
            wsum[16] = run;
        }
        __syncthreads();
        if (i < O_N) { int e = wsum[wv] + (v - x); offsets[i] = e; cursor[i] = e; }
        if (tid == 0) carry = wsum[16];
    }
    __syncthreads();
    if (tid == 0) offsets[O_N] = carry;
}

// slot list: for each edge, one entry per endpoint. value = (t<<1) | (0=s-half,1=o-half)
__global__ void fill_k(const int* __restrict__ edges, int* __restrict__ cursor,
                       int* __restrict__ slots) {
    int t = blockIdx.x * 256 + threadIdx.x;
    if (t < T_N) {
        int s = edges[2 * t], o = edges[2 * t + 1];
        int p = atomicAdd(&cursor[s], 1);
        slots[p] = t << 1;
        int q = atomicAdd(&cursor[o], 1);
        slots[q] = (t << 1) | 1;
    }
}

// CSR gather pooling: one wave per object; f32 accumulation within chunk;
// bf16 running value between chunks (>= precision of old per-atomic bf16 rounding).
// Division by counts stays fused in gemm3 (MODE 3).
template<bool FIRST>
__launch_bounds__(256)
__global__ void pool_k(const bf16_t* __restrict__ newT, const int* __restrict__ offsets,
                       const int* __restrict__ slots, bf16_t* __restrict__ pooledB,
                       int tbase, int tcount) {
    const int gw   = (blockIdx.x * 256 + threadIdx.x) >> 6;  // object id
    const int lane = threadIdx.x & 63;
    if (gw >= O_N) return;
    const int s0 = offsets[gw], s1 = offsets[gw + 1];
    float acc[8];
    #pragma unroll
    for (int l = 0; l < 8; l++) acc[l] = 0.f;
    for (int j = s0; j < s1; ++j) {
        int sl = slots[j];
        int lt = (sl >> 1) - tbase;
        if ((unsigned)lt >= (unsigned)tcount) continue;     // other chunk
        const bf16_t* p = newT + (size_t)lt * 1024 + (sl & 1) * 512 + lane * 8;
        bf16x8 v = *(const bf16x8*)p;                       // coalesced 1KB/wave
        #pragma unroll
        for (int l = 0; l < 8; l++) acc[l] += (float)v[l];
    }
    bf16_t* dst = pooledB + (size_t)gw * 512 + lane * 8;
    if constexpr (!FIRST) {
        bf16x8 prev = *(const bf16x8*)dst;
        #pragma unroll
        for (int l = 0; l < 8; l++) acc[l] += (float)prev[l];
    }
    bf16x8 o;
    #pragma unroll
    for (int l = 0; l < 8; l++) o[l] = (bf16_t)acc[l];
    *(bf16x8*)dst = o;
}

extern "C" void kernel_launch(void* const* d_in, const int* in_sizes, int n_in,
                              void* d_out, int out_size, void* d_ws, size_t ws_size,
                              hipStream_t stream) {
    const float* obj  = (const float*)d_in[0];
    const float* pred = (const float*)d_in[1];
    const int*   edges= (const int*)d_in[2];
    const float* W1 = (const float*)d_in[3];
    const float* b1 = (const float*)d_in[4];
    const float* W2 = (const float*)d_in[5];
    const float* b2 = (const float*)d_in[6];
    const float* W3 = (const float*)d_in[7];
    const float* b3 = (const float*)d_in[8];
    const float* W4 = (const float*)d_in[9];
    const float* b4 = (const float*)d_in[10];
    float* out = (float*)d_out;   // [new_obj O_N*128 | new_p T_N*128], f32

    char* ws = (char*)d_ws;
    auto AL = [](size_t x) { return (x + 255) & ~(size_t)255; };

    // ---- fixed region ----
    size_t o_pooled = 0;
    size_t o_counts = AL(o_pooled + (size_t)O_N * 512 * 2);   // 102.4 MB pooled bf16
    size_t o_offs   = AL(o_counts + (size_t)O_N * 4);
    size_t o_curs   = AL(o_offs   + (size_t)(O_N + 1) * 4);
    size_t o_slots  = AL(o_curs   + (size_t)O_N * 4);
    size_t o_w1     = AL(o_slots  + (size_t)2 * T_N * 4);     // 1.6 MB slots
    size_t o_w2     = AL(o_w1 + (size_t)384 * 512 * 2);
    size_t o_w3     = AL(o_w2 + (size_t)512 * 1152 * 2);
    size_t o_w4     = AL(o_w3 + (size_t)512 * 512 * 2);
    size_t o_chunk  = AL(o_w4 + (size_t)512 * 128 * 2);

    // chunk region: h (R x 512 bf16) then newT (R x 1024 bf16); t3 aliases chunk base
    size_t need2 = o_chunk + AL((size_t)100000 * 1024) + (size_t)100000 * 2048; // ~415 MB
    size_t need4 = o_chunk + AL((size_t)50000  * 1024) + (size_t)50000  * 2048; // ~261 MB

    if (ws_size >= need4) {
        const int NCH = (ws_size >= need2) ? 2 : 4;
        const int R   = T_N / NCH;

        bf16_t* pooledB = (bf16_t*)(ws + o_pooled);
        float*  counts  = (float*)(ws + o_counts);
        int*    offs    = (int*)(ws + o_offs);
        int*    curs    = (int*)(ws + o_curs);
        int*    slots   = (int*)(ws + o_slots);
        bf16_t* W1t     = (bf16_t*)(ws + o_w1);
        bf16_t* W2t     = (bf16_t*)(ws + o_w2);
        bf16_t* W3t     = (bf16_t*)(ws + o_w3);
        bf16_t* W4t     = (bf16_t*)(ws + o_w4);
        bf16_t* hbuf    = (bf16_t*)(ws + o_chunk);
        bf16_t* newT    = (bf16_t*)(ws + o_chunk + AL((size_t)R * 1024));
        bf16_t* t3      = (bf16_t*)(ws + o_chunk);   // reuse after pools done

        hipMemsetAsync(counts, 0, (size_t)O_N * 4, stream);

        transpose_k<<<(384 * 512  + 255) / 256, 256, 0, stream>>>(W1, W1t, 384, 512);
        transpose_k<<<(512 * 1152 + 255) / 256, 256, 0, stream>>>(W2, W2t, 512, 1152);
        transpose_k<<<(512 * 512  + 255) / 256, 256, 0, stream>>>(W3, W3t, 512, 512);
        transpose_k<<<(512 * 128  + 255) / 256, 256, 0, stream>>>(W4, W4t, 512, 128);
        counts_k<<<(T_N + 255) / 256, 256, 0, stream>>>(edges, counts);
        scan_k<<<1, 1024, 0, stream>>>(counts, offs, curs);
        fill_k<<<(T_N + 255) / 256, 256, 0, stream>>>(edges, curs, slots);

        const int MB = (R + 127) / 128;
        for (int c = 0; c < NCH; ++c) {
            const int row0 = c * R;
            gemm_k<1, 512, 384><<<dim3(4, MB), 256, 0, stream>>>(
                nullptr, obj, pred + (size_t)row0 * 128, edges + 2 * row0,
                nullptr, W1t, b1, hbuf, nullptr, R);
            gemm_k<2, 1152, 512><<<dim3(9, MB), 256, 0, stream>>>(
                hbuf, nullptr, nullptr, nullptr,
                nullptr, W2t, b2, newT,
                out + (size_t)O_N * 128 + (size_t)row0 * 128, R);
            if (c == 0)
                pool_k<true><<<(O_N * 64 + 255) / 256, 256, 0, stream>>>(
                    newT, offs, slots, pooledB, row0, R);
            else
                pool_k<false><<<(O_N * 64 + 255) / 256, 256, 0, stream>>>(
                    newT, offs, slots, pooledB, row0, R);
        }
        // t3 = relu((pooledB/max(counts,1)) @ W3 + b3)   (div fused into A-stage)
        gemm_k<3, 512, 512><<<dim3(4, 782), 256, 0, stream>>>(
            pooledB, nullptr, nullptr, nullptr, counts,
            W3t, b3, t3, nullptr, O_N);
        // new_obj = relu(t3 @ W4 + b4)
        gemm_k<4, 128, 512><<<dim3(1, 782), 256, 0, stream>>>(
            t3, nullptr, nullptr, nullptr, nullptr,
            W4t, b4, nullptr, out, O_N);
    } else {
        // ---- fallback: previous session's atomic path (~207.5 MB workspace) ----
        bf16_t* pooledB = (bf16_t*)(ws + 0);
        float*  counts  = (float*)(ws + 102400000);
        bf16_t* hbuf    = (bf16_t*)(ws + 102800128);
        bf16_t* t3      = hbuf;
        bf16_t* W1t     = (bf16_t*)(ws + 205200128);
        bf16_t* W2t     = (bf16_t*)(ws + 205593344);
        bf16_t* W3t     = (bf16_t*)(ws + 206772992);
        bf16_t* W4t     = (bf16_t*)(ws + 207297280);

        hipMemsetAsync(pooledB, 0, 102800000, stream);   // pooledB + counts

        transpose_k<<<(384 * 512  + 255) / 256, 256, 0, stream>>>(W1, W1t, 384, 512);
        transpose_k<<<(512 * 1152 + 255) / 256, 256, 0, stream>>>(W2, W2t, 512, 1152);
        transpose_k<<<(512 * 512  + 255) / 256, 256, 0, stream>>>(W3, W3t, 512, 512);
        transpose_k<<<(512 * 128  + 255) / 256, 256, 0, stream>>>(W4, W4t, 512, 128);
        counts_k<<<(T_N + 255) / 256, 256, 0, stream>>>(edges, counts);

        for (int c = 0; c < 2; ++c) {
            const int row0 = c * 100000;
            gemm_k<1, 512, 384><<<dim3(4, 782), 256, 0, stream>>>(
                nullptr, obj, pred + (size_t)row0 * 128, edges + 2 * row0,
                nullptr, W1t, b1, hbuf, nullptr, 100000);
            gemm_k<5, 1152, 512><<<dim3(9, 782), 256, 0, stream>>>(
                hbuf, nullptr, nullptr, edges + 2 * row0,
                nullptr, W2t, b2, pooledB,
                out + (size_t)O_N * 128 + (size_t)row0 * 128, 100000);
        }
        gemm_k<3, 512, 512><<<dim3(4, 782), 256, 0, stream>>>(
            pooledB, nullptr, nullptr, nullptr, counts,
            W3t, b3, t3, nullptr, O_N);
        gemm_k<4, 128, 512><<<dim3(1, 782), 256, 0, stream>>>(
            t3, nullptr, nullptr, nullptr, nullptr,
            W4t, b4, nullptr, out, O_N);
    }
}

// Round 2
// 1483.563 us; speedup vs baseline: 1.4725x; 1.0756x over previous
//
#include <hip/hip_runtime.h>
#include <hip/hip_bf16.h>

typedef __bf16 bf16_t;
typedef __attribute__((ext_vector_type(8))) __bf16 bf16x8;
typedef __attribute__((ext_vector_type(4))) __bf16 bf16x4;
typedef __attribute__((ext_vector_type(4))) float f32x4;

#define O_N 100000
#define T_N 200000
#define LDA 72    // padded LDS row stride (elems): 144B -> 2-way bank aliasing (free, m136)
#define LDN 136   // epilogue restage stride: 272B = 17x16B (aligned), ~4-way write / 2-way read

__device__ __forceinline__ bf16x8 cvt8(const float* p) {
    f32x4 a = *(const f32x4*)p;
    f32x4 b = *(const f32x4*)(p + 4);
    bf16x8 v;
    v[0] = (bf16_t)a[0]; v[1] = (bf16_t)a[1]; v[2] = (bf16_t)a[2]; v[3] = (bf16_t)a[3];
    v[4] = (bf16_t)b[0]; v[5] = (bf16_t)b[1]; v[6] = (bf16_t)b[2]; v[7] = (bf16_t)b[3];
    return v;
}

// Bijective chunked XCD swizzle (m204): consecutive NEW ids land on ONE XCD, so the
// gridDim.x n-blocks sharing an A-panel hit the same per-XCD L2.
__device__ __forceinline__ void swz_block(int& mbase, int& nbase) {
    const int gx   = gridDim.x;
    const int nwg  = gx * gridDim.y;
    const int orig = blockIdx.y * gx + blockIdx.x;
    const int q = nwg >> 3, r = nwg & 7;
    const int xcd = orig & 7, lo = orig >> 3;
    const int base = (xcd < r) ? xcd * (q + 1) : r * (q + 1) + (xcd - r) * q;
    const int id = base + lo;
    nbase = (id % gx) * 128;
    mbase = (id / gx) * 128;
}

// MODE 1: A = gather-concat(objF[s]|predF|objF[o]) f32->bf16 -> CoutB = h (bf16)
// MODE 2: A = h (bf16); MFMA operand-swapped (transposed C in regs):
//         n-blocks 0-3 / 5-8: LDS-restage C-tile -> coalesced bf16x8 row stores to newT;
//         block 4: f32x4 -> newp.  NO atomics (pooling via CSR pool_k).  CoutB = newT.
// MODE 3: A = pooledB (bf16) * 1/max(counts,1) (fused div) -> CoutB = t3 (bf16)
// MODE 4: A = t3 (bf16) -> CoutF = new_obj (f32)
// MODE 5: legacy atomic-scatter epilogue (small-workspace fallback only)
template<int MODE, int N, int K>
__launch_bounds__(256)
__global__ void gemm_k(const bf16_t* __restrict__ A,
                       const float*  __restrict__ AobjF,
                       const float*  __restrict__ ApredF,
                       const int*    __restrict__ edges,
                       const float*  __restrict__ countsIn,
                       const bf16_t* __restrict__ Bt,     // N x K row-major bf16
                       const float*  __restrict__ bias,   // length N, f32
                       bf16_t*       __restrict__ CoutB,  // MODE1: h, MODE2: newT, MODE3: t3
                       float*        __restrict__ CoutF,  // MODE2/5: newp base; MODE4: new_obj
                       int M)
{
    __shared__ bf16_t smem[2 * 128 * LDA];   // lA | lB; epilogue reuses as 128 x LDN tile
    bf16_t* lA = smem;
    bf16_t* lB = smem + 128 * LDA;
    __shared__ int sIdxL[128], oIdxL[128];

    const int tid  = threadIdx.x;
    const int lane = tid & 63;
    const int wv   = tid >> 6;
    const int wr   = (wv >> 1) * 64;   // wave row base in 128-tile
    const int wc   = (wv & 1) * 64;    // wave col base
    const int fr   = lane & 15;        // m/n within 16-tile
    const int fk   = (lane >> 4) * 8;  // k offset within 32
    int mbase, nbase;
    swz_block(mbase, nbase);

    if constexpr (MODE == 1 || MODE == 5) {
        if (tid < 128) {
            int g = mbase + tid; if (g > M - 1) g = M - 1;
            sIdxL[tid] = edges[2 * g];
            oIdxL[tid] = edges[2 * g + 1];
        }
    }
    __syncthreads();

    f32x4 acc[4][4];
    #pragma unroll
    for (int i = 0; i < 4; i++)
        #pragma unroll
        for (int j = 0; j < 4; j++)
            acc[i][j] = (f32x4){0.f, 0.f, 0.f, 0.f};

    const int KT = K / 64;
    for (int kt = 0; kt < KT; ++kt) {
        const int k0 = kt * 64;
        // ---- stage A tile (128 rows x 64 k) : 8 elems/thread x4 ----
        #pragma unroll
        for (int t = 0; t < 4; ++t) {
            int e   = t * 2048 + tid * 8;
            int row = e >> 6;
            int col = e & 63;
            int grow = mbase + row; if (grow > M - 1) grow = M - 1;
            bf16x8 v;
            if constexpr (MODE == 1) {
                int k = k0 + col;  // 64-chunk lies in one 128-wide segment
                const float* gp;
                if (k < 128)      gp = AobjF  + (size_t)sIdxL[row] * 128 + k;
                else if (k < 256) gp = ApredF + (size_t)grow * 128 + (k - 128);
                else              gp = AobjF  + (size_t)oIdxL[row] * 128 + (k - 256);
                v = cvt8(gp);
            } else if constexpr (MODE == 3) {
                const bf16_t* pr = A + (size_t)grow * 512 + k0 + col;
                float c = countsIn[grow]; c = c > 1.f ? c : 1.f;
                float rc = 1.f / c;
                bf16x8 raw = *(const bf16x8*)pr;
                #pragma unroll
                for (int l = 0; l < 8; l++) v[l] = (bf16_t)((float)raw[l] * rc);
            } else {
                v = *(const bf16x8*)(A + (size_t)grow * K + k0 + col);
            }
            *(bf16x8*)&lA[row * LDA + col] = v;
        }
        // ---- stage B tile (128 n x 64 k), bf16 source ----
        #pragma unroll
        for (int t = 0; t < 4; ++t) {
            int e   = t * 2048 + tid * 8;
            int row = e >> 6;
            int col = e & 63;
            bf16x8 v = *(const bf16x8*)(Bt + (size_t)(nbase + row) * K + k0 + col);
            *(bf16x8*)&lB[row * LDA + col] = v;
        }
        __syncthreads();

        #pragma unroll
        for (int ks = 0; ks < 64; ks += 32) {
            bf16x8 af[4], bf[4];
            #pragma unroll
            for (int i = 0; i < 4; i++)
                af[i] = *(const bf16x8*)&lA[(wr + i * 16 + fr) * LDA + ks + fk];
            #pragma unroll
            for (int j = 0; j < 4; j++)
                bf[j] = *(const bf16x8*)&lB[(wc + j * 16 + fr) * LDA + ks + fk];
            #pragma unroll
            for (int i = 0; i < 4; i++)
                #pragma unroll
                for (int j = 0; j < 4; j++) {
                    if constexpr (MODE == 2 || MODE == 5)
                        // swapped operands: acc holds C^T -> lane owns 4 consecutive n
                        acc[i][j] = __builtin_amdgcn_mfma_f32_16x16x32_bf16(
                            bf[j], af[i], acc[i][j], 0, 0, 0);
                    else
                        acc[i][j] = __builtin_amdgcn_mfma_f32_16x16x32_bf16(
                            af[i], bf[j], acc[i][j], 0, 0, 0);
                }
        }
        __syncthreads();
    }

    if constexpr (MODE == 2) {
        // transposed D: col(lane&15)=m (edge row), row((lane>>4)*4+r)=n (out col)
        const bool isNewp = (nbase == 512);
        const int  cb     = (nbase < 512) ? nbase : (nbase - 128);
        if (isNewp) {
            // direct f32 stores (precision: newp stays f32)
            #pragma unroll
            for (int j = 0; j < 4; j++) {
                int nl = wc + j * 16 + (lane >> 4) * 4;
                f32x4 bv = *(const f32x4*)&bias[nbase + nl];
                #pragma unroll
                for (int i = 0; i < 4; i++) {
                    int ml   = wr + i * 16 + fr;
                    int grow = mbase + ml;
                    if (grow >= M) continue;
                    float v0 = acc[i][j][0] + bv[0]; v0 = v0 > 0.f ? v0 : 0.f;
                    float v1 = acc[i][j][1] + bv[1]; v1 = v1 > 0.f ? v1 : 0.f;
                    float v2 = acc[i][j][2] + bv[2]; v2 = v2 > 0.f ? v2 : 0.f;
                    float v3 = acc[i][j][3] + bv[3]; v3 = v3 > 0.f ? v3 : 0.f;
                    f32x4 o = {v0, v1, v2, v3};
                    *(f32x4*)&CoutF[(size_t)grow * 128 + nl] = o;   // nbase+nl-512 == nl
                }
            }
        } else {
            // restage C-tile in LDS (m-major), then coalesced row stores
            #pragma unroll
            for (int j = 0; j < 4; j++) {
                int nl = wc + j * 16 + (lane >> 4) * 4;
                f32x4 bv = *(const f32x4*)&bias[nbase + nl];
                #pragma unroll
                for (int i = 0; i < 4; i++) {
                    int ml = wr + i * 16 + fr;
                    float v0 = acc[i][j][0] + bv[0]; v0 = v0 > 0.f ? v0 : 0.f;
                    float v1 = acc[i][j][1] + bv[1]; v1 = v1 > 0.f ? v1 : 0.f;
                    float v2 = acc[i][j][2] + bv[2]; v2 = v2 > 0.f ? v2 : 0.f;
                    float v3 = acc[i][j][3] + bv[3]; v3 = v3 > 0.f ? v3 : 0.f;
                    bf16x4 pv;
                    pv[0] = (bf16_t)v0; pv[1] = (bf16_t)v1;
                    pv[2] = (bf16_t)v2; pv[3] = (bf16_t)v3;
                    *(bf16x4*)&smem[ml * LDN + nl] = pv;
                }
            }
            __syncthreads();
            #pragma unroll
            for (int rr = 0; rr < 8; ++rr) {
                int row  = rr * 16 + (tid >> 4);
                int grow = mbase + row;
                if (grow >= M) continue;
                bf16x8 v = *(const bf16x8*)&smem[row * LDN + (tid & 15) * 8];
                *(bf16x8*)&CoutB[(size_t)grow * 1024 + cb + (tid & 15) * 8] = v;
            }
        }
    } else if constexpr (MODE == 5) {
        // legacy atomic scatter (fallback path only)
        const bool isNewp = (nbase == 512);
        const bool isS    = (nbase < 512);
        const int* idxArr = isS ? sIdxL : oIdxL;
        const int  cb     = isS ? nbase : (nbase - 640);   // pooled col base
        #pragma unroll
        for (int j = 0; j < 4; j++) {
            int nl = wc + j * 16 + (lane >> 4) * 4;
            f32x4 bv = *(const f32x4*)&bias[nbase + nl];
            #pragma unroll
            for (int i = 0; i < 4; i++) {
                int ml   = wr + i * 16 + fr;
                int grow = mbase + ml;
                if (grow >= M) continue;
                float v0 = acc[i][j][0] + bv[0]; v0 = v0 > 0.f ? v0 : 0.f;
                float v1 = acc[i][j][1] + bv[1]; v1 = v1 > 0.f ? v1 : 0.f;
                float v2 = acc[i][j][2] + bv[2]; v2 = v2 > 0.f ? v2 : 0.f;
                float v3 = acc[i][j][3] + bv[3]; v3 = v3 > 0.f ? v3 : 0.f;
                if (isNewp) {
                    f32x4 o = {v0, v1, v2, v3};
                    *(f32x4*)&CoutF[(size_t)grow * 128 + nl] = o;
                } else {
                    int idx = idxArr[ml];
                    __hip_bfloat162 p0, p1;
                    p0.x = __float2bfloat16(v0); p0.y = __float2bfloat16(v1);
                    p1.x = __float2bfloat16(v2); p1.y = __float2bfloat16(v3);
                    __hip_bfloat162* base =
                        (__hip_bfloat162*)(CoutB + (size_t)idx * 512 + cb + nl);
                    unsafeAtomicAdd(base,     p0);
                    unsafeAtomicAdd(base + 1, p1);
                }
            }
        }
    } else {
        // normal D: col(lane&15)=n, row((lane>>4)*4+r)=m  [m89-verified]
        #pragma unroll
        for (int j = 0; j < 4; j++) {
            int col = nbase + wc + j * 16 + fr;
            float bval = bias[col];
            #pragma unroll
            for (int i = 0; i < 4; i++) {
                #pragma unroll
                for (int r = 0; r < 4; r++) {
                    int rl   = wr + i * 16 + (lane >> 4) * 4 + r;
                    int grow = mbase + rl;
                    if (grow >= M) continue;
                    float v = acc[i][j][r] + bval;
                    v = v > 0.f ? v : 0.f;
                    if constexpr (MODE == 4)
                        CoutF[(size_t)grow * N + col] = v;
                    else
                        CoutB[(size_t)grow * N + col] = (bf16_t)v;
                }
            }
        }
    }
}

// f32 in (K x N row-major) -> bf16 out (N x K row-major)
__global__ void transpose_k(const float* __restrict__ in, bf16_t* __restrict__ out,
                            int K, int N) {
    int idx = blockIdx.x * 256 + threadIdx.x;
    if (idx < K * N) {
        int k = idx / N, n = idx - k * N;
        out[n * K + k] = (bf16_t)in[idx];
    }
}

__global__ void counts_k(const int* __restrict__ edges, float* __restrict__ counts) {
    int t = blockIdx.x * 256 + threadIdx.x;
    if (t < T_N) {
        unsafeAtomicAdd(&counts[edges[2 * t]],     1.f);
        unsafeAtomicAdd(&counts[edges[2 * t + 1]], 1.f);
    }
}

// Exclusive prefix sum of (int)counts over O_N -> offsets[0..O_N], cursor=offsets.
__launch_bounds__(1024)
__global__ void scan_k(const float* __restrict__ counts, int* __restrict__ offsets,
                       int* __restrict__ cursor) {
    __shared__ int wsum[17];
    __shared__ int carry;
    const int tid = threadIdx.x, lane = tid & 63, wv = tid >> 6;
    if (tid == 0) carry = 0;
    for (int base = 0; base < O_N; base += 1024) {
        __syncthreads();                       // prev-iter wsum readers done
        int i = base + tid;
        int x = (i < O_N) ? (int)counts[i] : 0;
        int v = x;
        #pragma unroll
        for (int d = 1; d < 64; d <<= 1) {
            int u = __shfl_up(v, d, 64);
            if (lane >= d) v += u;
        }
        if (lane == 63) wsum[wv] = v;          // wave inclusive total
        __syncthreads();
        if (tid == 0) {                        // serial 16-elem exclusive scan
            int run = carry;
            #pragma unroll
            for (int k = 0; k < 16; ++k) { int t2 = wsum[k]; wsum[k] = run; run += t2; }
            wsum[16] = run;
        }
        __syncthreads();
        if (i < O_N) { int e = wsum[wv] + (v - x); offsets[i] = e; cursor[i] = e; }
        if (tid == 0) carry = wsum[16];
    }
    __syncthreads();
    if (tid == 0) offsets[O_N] = carry;
}

// slot list: for each edge, one entry per endpoint. value = (t<<1) | (0=s-half,1=o-half)
__global__ void fill_k(const int* __restrict__ edges, int* __restrict__ cursor,
                       int* __restrict__ slots) {
    int t = blockIdx.x * 256 + threadIdx.x;
    if (t < T_N) {
        int s = edges[2 * t], o = edges[2 * t + 1];
        int p = atomicAdd(&cursor[s], 1);
        slots[p] = t << 1;
        int q = atomicAdd(&cursor[o], 1);
        slots[q] = (t << 1) | 1;
    }
}

// CSR gather pooling: one wave per object; f32 accumulation within chunk;
// bf16 running value between chunks. Division by counts stays fused in gemm3 (MODE 3).
template<bool FIRST>
__launch_bounds__(256)
__global__ void pool_k(const bf16_t* __restrict__ newT, const int* __restrict__ offsets,
                       const int* __restrict__ slots, bf16_t* __restrict__ pooledB,
                       int tbase, int tcount) {
    const int gw   = (blockIdx.x * 256 + threadIdx.x) >> 6;  // object id
    const int lane = threadIdx.x & 63;
    if (gw >= O_N) return;
    const int s0 = offsets[gw], s1 = offsets[gw + 1];
    float acc[8];
    #pragma unroll
    for (int l = 0; l < 8; l++) acc[l] = 0.f;
    for (int j = s0; j < s1; ++j) {
        int sl = slots[j];
        int lt = (sl >> 1) - tbase;
        if ((unsigned)lt >= (unsigned)tcount) continue;     // other chunk
        const bf16_t* p = newT + (size_t)lt * 1024 + (sl & 1) * 512 + lane * 8;
        bf16x8 v = *(const bf16x8*)p;                       // coalesced 1KB/wave
        #pragma unroll
        for (int l = 0; l < 8; l++) acc[l] += (float)v[l];
    }
    bf16_t* dst = pooledB + (size_t)gw * 512 + lane * 8;
    if constexpr (!FIRST) {
        bf16x8 prev = *(const bf16x8*)dst;
        #pragma unroll
        for (int l = 0; l < 8; l++) acc[l] += (float)prev[l];
    }
    bf16x8 o;
    #pragma unroll
    for (int l = 0; l < 8; l++) o[l] = (bf16_t)acc[l];
    *(bf16x8*)dst = o;
}

extern "C" void kernel_launch(void* const* d_in, const int* in_sizes, int n_in,
                              void* d_out, int out_size, void* d_ws, size_t ws_size,
                              hipStream_t stream) {
    const float* obj  = (const float*)d_in[0];
    const float* pred = (const float*)d_in[1];
    const int*   edges= (const int*)d_in[2];
    const float* W1 = (const float*)d_in[3];
    const float* b1 = (const float*)d_in[4];
    const float* W2 = (const float*)d_in[5];
    const float* b2 = (const float*)d_in[6];
    const float* W3 = (const float*)d_in[7];
    const float* b3 = (const float*)d_in[8];
    const float* W4 = (const float*)d_in[9];
    const float* b4 = (const float*)d_in[10];
    float* out = (float*)d_out;   // [new_obj O_N*128 | new_p T_N*128], f32

    char* ws = (char*)d_ws;
    auto AL = [](size_t x) { return (x + 255) & ~(size_t)255; };

    // ---- fixed region ----
    size_t o_pooled = 0;
    size_t o_counts = AL(o_pooled + (size_t)O_N * 512 * 2);   // 102.4 MB pooled bf16
    size_t o_offs   = AL(o_counts + (size_t)O_N * 4);
    size_t o_curs   = AL(o_offs   + (size_t)(O_N + 1) * 4);
    size_t o_slots  = AL(o_curs   + (size_t)O_N * 4);
    size_t o_w1     = AL(o_slots  + (size_t)2 * T_N * 4);     // 1.6 MB slots
    size_t o_w2     = AL(o_w1 + (size_t)384 * 512 * 2);
    size_t o_w3     = AL(o_w2 + (size_t)512 * 1152 * 2);
    size_t o_w4     = AL(o_w3 + (size_t)512 * 512 * 2);
    size_t o_chunk  = AL(o_w4 + (size_t)512 * 128 * 2);

    // chunk region: h (R x 512 bf16) then newT (R x 1024 bf16); t3 aliases chunk base
    size_t need2 = o_chunk + AL((size_t)100000 * 1024) + (size_t)100000 * 2048; // ~415 MB
    size_t need4 = o_chunk + AL((size_t)50000  * 1024) + (size_t)50000  * 2048; // ~261 MB

    if (ws_size >= need4) {
        const int NCH = (ws_size >= need2) ? 2 : 4;
        const int R   = T_N / NCH;

        bf16_t* pooledB = (bf16_t*)(ws + o_pooled);
        float*  counts  = (float*)(ws + o_counts);
        int*    offs    = (int*)(ws + o_offs);
        int*    curs    = (int*)(ws + o_curs);
        int*    slots   = (int*)(ws + o_slots);
        bf16_t* W1t     = (bf16_t*)(ws + o_w1);
        bf16_t* W2t     = (bf16_t*)(ws + o_w2);
        bf16_t* W3t     = (bf16_t*)(ws + o_w3);
        bf16_t* W4t     = (bf16_t*)(ws + o_w4);
        bf16_t* hbuf    = (bf16_t*)(ws + o_chunk);
        bf16_t* newT    = (bf16_t*)(ws + o_chunk + AL((size_t)R * 1024));
        bf16_t* t3      = (bf16_t*)(ws + o_chunk);   // reuse after pools done

        hipMemsetAsync(counts, 0, (size_t)O_N * 4, stream);

        transpose_k<<<(384 * 512  + 255) / 256, 256, 0, stream>>>(W1, W1t, 384, 512);
        transpose_k<<<(512 * 1152 + 255) / 256, 256, 0, stream>>>(W2, W2t, 512, 1152);
        transpose_k<<<(512 * 512  + 255) / 256, 256, 0, stream>>>(W3, W3t, 512, 512);
        transpose_k<<<(512 * 128  + 255) / 256, 256, 0, stream>>>(W4, W4t, 512, 128);
        counts_k<<<(T_N + 255) / 256, 256, 0, stream>>>(edges, counts);
        scan_k<<<1, 1024, 0, stream>>>(counts, offs, curs);
        fill_k<<<(T_N + 255) / 256, 256, 0, stream>>>(edges, curs, slots);

        const int MB = (R + 127) / 128;
        for (int c = 0; c < NCH; ++c) {
            const int row0 = c * R;
            gemm_k<1, 512, 384><<<dim3(4, MB), 256, 0, stream>>>(
                nullptr, obj, pred + (size_t)row0 * 128, edges + 2 * row0,
                nullptr, W1t, b1, hbuf, nullptr, R);
            gemm_k<2, 1152, 512><<<dim3(9, MB), 256, 0, stream>>>(
                hbuf, nullptr, nullptr, nullptr,
                nullptr, W2t, b2, newT,
                out + (size_t)O_N * 128 + (size_t)row0 * 128, R);
            if (c == 0)
                pool_k<true><<<(O_N * 64 + 255) / 256, 256, 0, stream>>>(
                    newT, offs, slots, pooledB, row0, R);
            else
                pool_k<false><<<(O_N * 64 + 255) / 256, 256, 0, stream>>>(
                    newT, offs, slots, pooledB, row0, R);
        }
        // t3 = relu((pooledB/max(counts,1)) @ W3 + b3)   (div fused into A-stage)
        gemm_k<3, 512, 512><<<dim3(4, 782), 256, 0, stream>>>(
            pooledB, nullptr, nullptr, nullptr, counts,
            W3t, b3, t3, nullptr, O_N);
        // new_obj = relu(t3 @ W4 + b4)
        gemm_k<4, 128, 512><<<dim3(1, 782), 256, 0, stream>>>(
            t3, nullptr, nullptr, nullptr, nullptr,
            W4t, b4, nullptr, out, O_N);
    } else {
        // ---- fallback: atomic path (~207.5 MB workspace) ----
        bf16_t* pooledB = (bf16_t*)(ws + 0);
        float*  counts  = (float*)(ws + 102400000);
        bf16_t* hbuf    = (bf16_t*)(ws + 102800128);
        bf16_t* t3      = hbuf;
        bf16_t* W1t     = (bf16_t*)(ws + 205200128);
        bf16_t* W2t     = (bf16_t*)(ws + 205593344);
        bf16_t* W3t     = (bf16_t*)(ws + 206772992);
        bf16_t* W4t     = (bf16_t*)(ws + 207297280);

        hipMemsetAsync(pooledB, 0, 102800000, stream);   // pooledB + counts

        transpose_k<<<(384 * 512  + 255) / 256, 256, 0, stream>>>(W1, W1t, 384, 512);
        transpose_k<<<(512 * 1152 + 255) / 256, 256, 0, stream>>>(W2, W2t, 512, 1152);
        transpose_k<<<(512 * 512  + 255) / 256, 256, 0, stream>>>(W3, W3t, 512, 512);
        transpose_k<<<(512 * 128  + 255) / 256, 256, 0, stream>>>(W4, W4t, 512, 128);
        counts_k<<<(T_N + 255) / 256, 256, 0, stream>>>(edges, counts);

        for (int c = 0; c < 2; ++c) {
            const int row0 = c * 100000;
            gemm_k<1, 512, 384><<<dim3(4, 782), 256, 0, stream>>>(
                nullptr, obj, pred + (size_t)row0 * 128, edges + 2 * row0,
                nullptr, W1t, b1, hbuf, nullptr, 100000);
            gemm_k<5, 1152, 512><<<dim3(9, 782), 256, 0, stream>>>(
                hbuf, nullptr, nullptr, edges + 2 * row0,
                nullptr, W2t, b2, pooledB,
                out + (size_t)O_N * 128 + (size_t)row0 * 128, 100000);
        }
        gemm_k<3, 512, 512><<<dim3(4, 782), 256, 0, stream>>>(
            pooledB, nullptr, nullptr, nullptr, counts,
            W3t, b3, t3, nullptr, O_N);
        gemm_k<4, 128, 512><<<dim3(1, 782), 256, 0, stream>>>(
            t3, nullptr, nullptr, nullptr, nullptr,
            W4t, b4, nullptr, out, O_N);
    }
}